// Round 16
// baseline (123.199 us; speedup 1.0000x reference)
//
#include <hip/hip_runtime.h>
#include <math.h>

#define B_ 128
#define S_ 1024
#define D_ 256          // D == A == O == 256
#define XP 264          // LDS bf16 row pitch for x/v tile (528 B, 16B-aligned)
#define TP 68           // LDS fp32 row pitch for transpose buffer (272 B, 16B-aligned)
#define ROWS 32         // rows per block
#define LOG2E  1.44269504f
#define LOG2E2 2.88539008f

using bf16x8 = __attribute__((ext_vector_type(8))) __bf16;
using bf16x4 = __attribute__((ext_vector_type(4))) __bf16;
using f32x4  = __attribute__((ext_vector_type(4))) float;

__device__ __forceinline__ float qred_add(float v) {   // reduce across 16-lane group
    v += __shfl_xor(v, 1); v += __shfl_xor(v, 2);
    v += __shfl_xor(v, 4); v += __shfl_xor(v, 8);
    return v;
}
__device__ __forceinline__ float wred_add(float x) {
#pragma unroll
    for (int off = 32; off > 0; off >>= 1) x += __shfl_xor(x, off, 64);
    return x;
}

// ---- prep: pack W, Uo (fp32 row-major [k][n]) into B-fragment-linear bf16.
__global__ __launch_bounds__(256) void k_prep(
    const float* __restrict__ W, const float* __restrict__ Uo,
    __bf16* __restrict__ Wf, __bf16* __restrict__ Uf)
{
    const int e = blockIdx.x * 256 + threadIdx.x;   // 0..65535
    const int frag = e >> 9, rem = e & 511;
    const int lane = rem >> 3, j = rem & 7;
    const int kk = frag >> 4, tn = frag & 15;
    const int k = kk * 32 + (lane >> 4) * 8 + j;
    const int n = tn * 16 + (lane & 15);
    Wf[e] = (__bf16)W[k * 256 + n];
    Uf[e] = (__bf16)Uo[k * 256 + n];
}

// ---- main fused kernel: 32 rows/block, 4 waves; wave w owns cols [64w, 64w+64).
// Round-13 structure (90.08 us best) with ONE lever: register total pushed under
// the 6-waves/SIMD boundary. r15's decomposition showed residency is worth
// ~1 us per occupancy point downward (96->104 regs = -1 block = +26 us); this
// tests the same lever upward: launch_bounds(256,6) (budget ~84) + ev/rs
// computed per-i in the epilogue (8 live floats, not 16). GEMM live set ~24 V
// + addressing fits ~52 V; 52V+32A=84 -> 6 blocks/CU cap (was 5).
// Falsifiers: WRITE_SIZE > 140,000 KB = spill -> revert to r13;
//             occupancy <= 44% w/o spill = reg-cap not the achieved binder.
__global__ __launch_bounds__(256, 6) void k_rows(
    const float* __restrict__ x, const float* __restrict__ mask,
    const __bf16* __restrict__ Wf, const float* __restrict__ bo,
    const float* __restrict__ u, const __bf16* __restrict__ Uf,
    float* __restrict__ e_out,    // [B*S] unnormalized exp(vu)*mask (alphas region)
    float* __restrict__ betas,    // [B*S, 256]
    float* __restrict__ part,     // [gridDim.x, 256] per-block out partials (ws)
    float* __restrict__ outraw,   // [B,256] atomic fallback accumulator
    const int use_part)
{
    // xs (bf16 x/v tile, 16896 B) aliased with trans (4 waves x 16 rows x TP fp32
    // = 17408 B). xs is dead once GEMM2's reads drain (barrier (d) orders).
    __shared__ __align__(16) char smem[4 * 16 * TP * 4];
    __bf16* xs   = (__bf16*)smem;
    float* trans = (float*)smem;
    __shared__ float red[4][ROWS];    // ||t||^2 partials, then beta row-sum partials
    __shared__ float red2[4][ROWS];   // vu partials
    const int tid = threadIdx.x, lane = tid & 63, w = tid >> 6;
    const int quad = lane >> 4, c = lane & 15;
    const int hi = lane >> 4, c4 = lane & 15;      // store-phase decomposition
    const int row0 = blockIdx.x * ROWS;
    const bf16x8* Wf8 = (const bf16x8*)Wf;
    const bf16x8* Uf8 = (const bf16x8*)Uf;

    // stage x[32][256] fp32 -> bf16 LDS
    {
        const float4* xg = (const float4*)(x + (size_t)row0 * D_);
#pragma unroll
        for (int it = 0; it < 8; ++it) {
            const int r = it * 4 + w;
            const float4 t = xg[r * 64 + lane];
            bf16x4 h; h[0] = (__bf16)t.x; h[1] = (__bf16)t.y; h[2] = (__bf16)t.z; h[3] = (__bf16)t.w;
            *(bf16x4*)(xs + r * XP + lane * 4) = h;
        }
    }

    __syncthreads();                                   // sync0: x staged

    // ---- GEMM1: t = x @ W
    f32x4 acc[2][4];                                   // reused by GEMM2 (32 AGPR total)
#pragma unroll
    for (int i = 0; i < 2; ++i)
#pragma unroll
        for (int j = 0; j < 4; ++j) acc[i][j] = (f32x4){0.f, 0.f, 0.f, 0.f};
#pragma unroll
    for (int kk = 0; kk < 8; ++kk) {
        bf16x8 a[2], b[4];
#pragma unroll
        for (int i = 0; i < 2; ++i)
            a[i] = *(const bf16x8*)(xs + (i * 16 + c) * XP + kk * 32 + quad * 8);
#pragma unroll
        for (int j = 0; j < 4; ++j)
            b[j] = Wf8[(kk * 16 + w * 4 + j) * 64 + lane];
#pragma unroll
        for (int i = 0; i < 2; ++i)
#pragma unroll
            for (int j = 0; j < 4; ++j)
                acc[i][j] = __builtin_amdgcn_mfma_f32_16x16x32_bf16(a[i], b[j], acc[i][j], 0, 0, 0);
    }

    // bias + row sum-of-squares partials
#pragma unroll
    for (int j = 0; j < 4; ++j) {
        const float bj = bo[w * 64 + j * 16 + c];
#pragma unroll
        for (int i = 0; i < 2; ++i)
#pragma unroll
            for (int r = 0; r < 4; ++r) acc[i][j][r] += bj;
    }
    {
        float myv = 0.f;
#pragma unroll
        for (int i = 0; i < 2; ++i)
#pragma unroll
            for (int r = 0; r < 4; ++r) {
                float s = 0.f;
#pragma unroll
                for (int j = 0; j < 4; ++j) s += acc[i][j][r] * acc[i][j][r];
                const float p = qred_add(s);
                if (c == i * 4 + r) myv = p;
            }
        if (c < 8) red[w][(c >> 2) * 16 + quad * 4 + (c & 3)] = myv;
    }
    __syncthreads();                                   // (a): norm partials visible;
                                                       //      GEMM1 xs reads done (v-write WAR)

    // inv2 = 2*log2e / ||t||: one v_rsq (clamp inside: t>=1e-24 <=> norm>=1e-12).
    float inv2[2][4];
#pragma unroll
    for (int i = 0; i < 2; ++i)
#pragma unroll
        for (int r = 0; r < 4; ++r) {
            const int row = i * 16 + quad * 4 + r;
            const float t = red[0][row] + red[1][row] + red[2][row] + red[3][row];
            inv2[i][r] = __builtin_amdgcn_rsqf(fmaxf(t, 1e-24f)) * LOG2E2;
        }

    // v = tanh(t/||t||): vu partials, write v (bf16) into xs (reuse).
    // LAST read of GEMM1's acc -- dead after this loop (enables AGPR reuse).
    float uj[4];
#pragma unroll
    for (int j = 0; j < 4; ++j) uj[j] = u[w * 64 + j * 16 + c];
    float vup[2][4];
#pragma unroll
    for (int i = 0; i < 2; ++i)
#pragma unroll
        for (int r = 0; r < 4; ++r) vup[i][r] = 0.f;
#pragma unroll
    for (int i = 0; i < 2; ++i)
#pragma unroll
        for (int j = 0; j < 4; ++j)
#pragma unroll
            for (int r = 0; r < 4; ++r) {
                const float e2 = __builtin_amdgcn_exp2f(acc[i][j][r] * inv2[i][r]);
                const float v  = (e2 - 1.f) * __builtin_amdgcn_rcpf(e2 + 1.f);
                vup[i][r] += v * uj[j];
                xs[(i * 16 + quad * 4 + r) * XP + (w * 64 + j * 16 + c)] = (__bf16)v;
            }
    // vu partials into red2 BEFORE the barrier (red2 has no prior readers).
    {
        float myv = 0.f;
#pragma unroll
        for (int i = 0; i < 2; ++i)
#pragma unroll
            for (int r = 0; r < 4; ++r) {
                const float p = qred_add(vup[i][r]);
                if (c == i * 4 + r) myv = p;
            }
        if (c < 8) red2[w][(c >> 2) * 16 + quad * 4 + (c & 3)] = myv;
    }
    __syncthreads();                                   // (b): v tile AND vu partials visible

    // early e_out store (ev for epilogue recomputed after (d) from red2, intact)
    if (tid < ROWS) {
        const float vu = red2[0][tid] + red2[1][tid] + red2[2][tid] + red2[3][tid];
        e_out[row0 + tid] = __expf(vu) * mask[row0 + tid];
    }

    // ---- GEMM2: vuo = v @ Uo  (accumulates into the SAME acc array -> AGPR reuse)
#pragma unroll
    for (int i = 0; i < 2; ++i)
#pragma unroll
        for (int j = 0; j < 4; ++j) acc[i][j] = (f32x4){0.f, 0.f, 0.f, 0.f};
#pragma unroll
    for (int kk = 0; kk < 8; ++kk) {
        bf16x8 a[2], b[4];
#pragma unroll
        for (int i = 0; i < 2; ++i)
            a[i] = *(const bf16x8*)(xs + (i * 16 + c) * XP + kk * 32 + quad * 8);
#pragma unroll
        for (int j = 0; j < 4; ++j)
            b[j] = Uf8[(kk * 16 + w * 4 + j) * 64 + lane];
#pragma unroll
        for (int i = 0; i < 2; ++i)
#pragma unroll
            for (int j = 0; j < 4; ++j)
                acc[i][j] = __builtin_amdgcn_mfma_f32_16x16x32_bf16(a[i], b[j], acc[i][j], 0, 0, 0);
    }

    // betas numerator: exp(vuo*m)*m = exp2(vuo*(m*log2e))*m  (no max shift:
    // |vuo| <= ~10, the shift cancels exactly in the ratio)
#pragma unroll
    for (int i = 0; i < 2; ++i)
#pragma unroll
        for (int r = 0; r < 4; ++r) {
            const float m  = mask[row0 + i * 16 + quad * 4 + r];
            const float m2 = m * LOG2E;
#pragma unroll
            for (int j = 0; j < 4; ++j)
                acc[i][j][r] = __builtin_amdgcn_exp2f(acc[i][j][r] * m2) * m;
        }
    // beta row-sum partials into red BEFORE the barrier (red's last reader was
    // inv2, pre-(b): barrier (b) orders -> no WAR hazard). GUARDED store (c<8).
    {
        float myv = 0.f;
#pragma unroll
        for (int i = 0; i < 2; ++i)
#pragma unroll
            for (int r = 0; r < 4; ++r) {
                float s = 0.f;
#pragma unroll
                for (int j = 0; j < 4; ++j) s += acc[i][j][r];
                const float p = qred_add(s);
                if (c == i * 4 + r) myv = p;
            }
        if (c < 8) red[w][(c >> 2) * 16 + quad * 4 + (c & 3)] = myv;
    }
    __syncthreads();                                   // (d): GEMM2 xs reads done (trans WAR)
                                                       //      AND beta sums visible

    // ---- epilogue: two-pass LDS transpose (16-row wave-private slice) ->
    //      coalesced nontemporal f32x4 stores, fused out-partials with x re-read.
    //      ev/rs computed PER-i at the use site (8 live floats, not 16) to keep
    //      peak VGPR under the 6-waves/SIMD budget.
    float* tw = trans + w * (16 * TP);
    f32x4 opart = (f32x4){0.f, 0.f, 0.f, 0.f};
#pragma unroll
    for (int i = 0; i < 2; ++i) {
        float evp[4], rsp[4];
#pragma unroll
        for (int p = 0; p < 4; ++p) {
            const int rr = i * 16 + hi + p * 4;
            const float vu = red2[0][rr] + red2[1][rr] + red2[2][rr] + red2[3][rr];
            evp[p] = __expf(vu) * mask[row0 + rr];
            const float s = red[0][rr] + red[1][rr] + red[2][rr] + red[3][rr];
            rsp[p] = __builtin_amdgcn_rcpf((s == 0.f) ? 1.f : s);
        }
        asm volatile("s_waitcnt lgkmcnt(0)" ::: "memory");  // WAR: prior trans reads drained
#pragma unroll
        for (int j = 0; j < 4; ++j)
#pragma unroll
            for (int r = 0; r < 4; ++r)
                tw[(quad * 4 + r) * TP + j * 16 + c] = acc[i][j][r];
        asm volatile("s_waitcnt lgkmcnt(0)" ::: "memory");  // RAW: writes visible
#pragma unroll
        for (int p = 0; p < 4; ++p) {
            const int rl = hi + p * 4;                      // local row 0..15
            f32x4 b4 = *(const f32x4*)&tw[rl * TP + c4 * 4];
            const float rsv = rsp[p];
            b4[0] *= rsv; b4[1] *= rsv; b4[2] *= rsv; b4[3] *= rsv;
            const size_t goff = (size_t)(row0 + i * 16 + rl) * D_ + w * 64 + c4 * 4;
            __builtin_nontemporal_store(b4, (f32x4*)&betas[goff]); // 256 B/16-lane group
            const float evv = evp[p];
            if (evv != 0.f) {                               // 16-lane-uniform skip
                const f32x4 x4 = *(const f32x4*)&x[goff];
                opart[0] += evv * b4[0] * x4[0];
                opart[1] += evv * b4[1] * x4[1];
                opart[2] += evv * b4[2] * x4[2];
                opart[3] += evv * b4[3] * x4[3];
            }
        }
    }
    // reduce across the 4 row-groups
#pragma unroll
    for (int k = 0; k < 4; ++k) {
        opart[k] += __shfl_xor(opart[k], 16);
        opart[k] += __shfl_xor(opart[k], 32);
    }
    if (lane < 16) {
        const int col = w * 64 + c4 * 4;
        if (use_part) {
            *(f32x4*)&part[(size_t)blockIdx.x * D_ + col] = opart;
        } else {
            const int b = row0 >> 10;
#pragma unroll
            for (int k = 0; k < 4; ++k) atomicAdd(&outraw[b * D_ + col + k], opart[k]);
        }
    }
}

// ---- final: Z per batch, normalize alphas in place, reduce out partials.
__global__ __launch_bounds__(256) void k_fin(
    const float* __restrict__ part, float* __restrict__ e_alphas,
    float* __restrict__ out, const int use_part)
{
    const int b = blockIdx.x;
    const int tid = threadIdx.x, lane = tid & 63, wid = tid >> 6;
    __shared__ float red[4];
    const int base = b * S_;
    float ev[4];
#pragma unroll
    for (int k = 0; k < 4; ++k) ev[k] = e_alphas[base + tid + 256 * k];
    float s = ev[0] + ev[1] + ev[2] + ev[3];
    s = wred_add(s);
    if (lane == 0) red[wid] = s;
    __syncthreads();
    const float Z = red[0] + red[1] + red[2] + red[3];
    const float Zr = 1.f / ((Z == 0.f) ? 1.f : Z);
#pragma unroll
    for (int k = 0; k < 4; ++k) e_alphas[base + tid + 256 * k] = ev[k] * Zr;

    float acc;
    if (use_part) {
        acc = 0.f;
#pragma unroll
        for (int k = 0; k < 32; ++k) acc += part[(size_t)(b * 32 + k) * D_ + tid];
    } else {
        acc = out[b * D_ + tid];
    }
    out[b * D_ + tid] = acc * Zr;
}

extern "C" void kernel_launch(void* const* d_in, const int* in_sizes, int n_in,
                              void* d_out, int out_size, void* d_ws, size_t ws_size,
                              hipStream_t stream) {
    const float* x    = (const float*)d_in[0];
    const float* mask = (const float*)d_in[1];
    const float* W    = (const float*)d_in[2];
    const float* bo   = (const float*)d_in[3];
    const float* u    = (const float*)d_in[4];
    const float* Uo   = (const float*)d_in[5];

    float* out    = (float*)d_out;             // [B, 256]
    float* alphas = out + B_ * D_;             // [B, S]
    float* betas  = alphas + (size_t)B_ * S_;  // [B, S, 256]

    __bf16* Wf = (__bf16*)d_ws;                // 128 KB
    __bf16* Uf = Wf + 65536;                   // 128 KB
    float* part = (float*)(Uf + 65536);        // 4096*256*4 = 4 MB (if it fits)

    const int nblk = B_ * S_ / ROWS;           // 4096
    const size_t need = 2 * 65536 * sizeof(__bf16) + (size_t)nblk * D_ * sizeof(float);
    const int use_part = (ws_size >= need) ? 1 : 0;

    if (!use_part)
        hipMemsetAsync(out, 0, (size_t)B_ * D_ * sizeof(float), stream);
    k_prep<<<256, 256, 0, stream>>>(W, Uo, Wf, Uf);
    k_rows<<<nblk, 256, 0, stream>>>(x, mask, Wf, bo, u, Uf, alphas, betas, part, out, use_part);
    k_fin <<<B_,   256, 0, stream>>>(part, alphas, out, use_part);
}

// Round 17
// 89.687 us; speedup vs baseline: 1.3737x; 1.3737x over previous
//
#include <hip/hip_runtime.h>
#include <math.h>

#define B_ 128
#define S_ 1024
#define D_ 256          // D == A == O == 256
#define XP 264          // LDS bf16 row pitch for x/v tile (528 B, 16B-aligned)
#define TP 68           // LDS fp32 row pitch for transpose buffer (272 B, 16B-aligned)
#define ROWS 32         // rows per block
#define LOG2E  1.44269504f
#define LOG2E2 2.88539008f

using bf16x8 = __attribute__((ext_vector_type(8))) __bf16;
using bf16x4 = __attribute__((ext_vector_type(4))) __bf16;
using f32x4  = __attribute__((ext_vector_type(4))) float;

__device__ __forceinline__ float qred_add(float v) {   // reduce across 16-lane group
    v += __shfl_xor(v, 1); v += __shfl_xor(v, 2);
    v += __shfl_xor(v, 4); v += __shfl_xor(v, 8);
    return v;
}
__device__ __forceinline__ float wred_add(float x) {
#pragma unroll
    for (int off = 32; off > 0; off >>= 1) x += __shfl_xor(x, off, 64);
    return x;
}

// ---- prep: pack W, Uo (fp32 row-major [k][n]) into B-fragment-linear bf16.
__global__ __launch_bounds__(256) void k_prep(
    const float* __restrict__ W, const float* __restrict__ Uo,
    __bf16* __restrict__ Wf, __bf16* __restrict__ Uf)
{
    const int e = blockIdx.x * 256 + threadIdx.x;   // 0..65535
    const int frag = e >> 9, rem = e & 511;
    const int lane = rem >> 3, j = rem & 7;
    const int kk = frag >> 4, tn = frag & 15;
    const int k = kk * 32 + (lane >> 4) * 8 + j;
    const int n = tn * 16 + (lane & 15);
    Wf[e] = (__bf16)W[k * 256 + n];
    Uf[e] = (__bf16)Uo[k * 256 + n];
}

// ---- main fused kernel: 32 rows/block, 4 waves; wave w owns cols [64w, 64w+64).
// REVERT to round-13 verbatim (90.08 us session best). Register map now fully
// charted: 96 regs (this config) = sweet spot; 104 regs (r15) = -1 block/CU =
// +26 us; forced 84 (r16) = spill = +33 us despite 61% occupancy. Occupancy
// above ~42% buys nothing; spill costs everything. VALU-trim (r11) and the
// 16-row trans slice (r13) are the two proven wins on the r4 skeleton.
__global__ __launch_bounds__(256, 3) void k_rows(
    const float* __restrict__ x, const float* __restrict__ mask,
    const __bf16* __restrict__ Wf, const float* __restrict__ bo,
    const float* __restrict__ u, const __bf16* __restrict__ Uf,
    float* __restrict__ e_out,    // [B*S] unnormalized exp(vu)*mask (alphas region)
    float* __restrict__ betas,    // [B*S, 256]
    float* __restrict__ part,     // [gridDim.x, 256] per-block out partials (ws)
    float* __restrict__ outraw,   // [B,256] atomic fallback accumulator
    const int use_part)
{
    // xs (bf16 x/v tile, 16896 B) aliased with trans (4 waves x 16 rows x TP fp32
    // = 17408 B). xs is dead once GEMM2's reads drain (barrier (d) orders).
    __shared__ __align__(16) char smem[4 * 16 * TP * 4];
    __bf16* xs   = (__bf16*)smem;
    float* trans = (float*)smem;
    __shared__ float red[4][ROWS];    // ||t||^2 partials, then beta row-sum partials
    __shared__ float red2[4][ROWS];   // vu partials
    const int tid = threadIdx.x, lane = tid & 63, w = tid >> 6;
    const int quad = lane >> 4, c = lane & 15;
    const int hi = lane >> 4, c4 = lane & 15;      // store-phase decomposition
    const int row0 = blockIdx.x * ROWS;
    const bf16x8* Wf8 = (const bf16x8*)Wf;
    const bf16x8* Uf8 = (const bf16x8*)Uf;

    // stage x[32][256] fp32 -> bf16 LDS
    {
        const float4* xg = (const float4*)(x + (size_t)row0 * D_);
#pragma unroll
        for (int it = 0; it < 8; ++it) {
            const int r = it * 4 + w;
            const float4 t = xg[r * 64 + lane];
            bf16x4 h; h[0] = (__bf16)t.x; h[1] = (__bf16)t.y; h[2] = (__bf16)t.z; h[3] = (__bf16)t.w;
            *(bf16x4*)(xs + r * XP + lane * 4) = h;
        }
    }

    __syncthreads();                                   // sync0: x staged

    // ---- GEMM1: t = x @ W
    f32x4 acc[2][4];                                   // reused by GEMM2 (32 AGPR total)
#pragma unroll
    for (int i = 0; i < 2; ++i)
#pragma unroll
        for (int j = 0; j < 4; ++j) acc[i][j] = (f32x4){0.f, 0.f, 0.f, 0.f};
#pragma unroll
    for (int kk = 0; kk < 8; ++kk) {
        bf16x8 a[2], b[4];
#pragma unroll
        for (int i = 0; i < 2; ++i)
            a[i] = *(const bf16x8*)(xs + (i * 16 + c) * XP + kk * 32 + quad * 8);
#pragma unroll
        for (int j = 0; j < 4; ++j)
            b[j] = Wf8[(kk * 16 + w * 4 + j) * 64 + lane];
#pragma unroll
        for (int i = 0; i < 2; ++i)
#pragma unroll
            for (int j = 0; j < 4; ++j)
                acc[i][j] = __builtin_amdgcn_mfma_f32_16x16x32_bf16(a[i], b[j], acc[i][j], 0, 0, 0);
    }

    // bias + row sum-of-squares partials
#pragma unroll
    for (int j = 0; j < 4; ++j) {
        const float bj = bo[w * 64 + j * 16 + c];
#pragma unroll
        for (int i = 0; i < 2; ++i)
#pragma unroll
            for (int r = 0; r < 4; ++r) acc[i][j][r] += bj;
    }
    {
        float myv = 0.f;
#pragma unroll
        for (int i = 0; i < 2; ++i)
#pragma unroll
            for (int r = 0; r < 4; ++r) {
                float s = 0.f;
#pragma unroll
                for (int j = 0; j < 4; ++j) s += acc[i][j][r] * acc[i][j][r];
                const float p = qred_add(s);
                if (c == i * 4 + r) myv = p;
            }
        if (c < 8) red[w][(c >> 2) * 16 + quad * 4 + (c & 3)] = myv;
    }
    __syncthreads();                                   // (a): norm partials visible;
                                                       //      GEMM1 xs reads done (v-write WAR)

    // inv2 = 2*log2e / ||t||: one v_rsq (clamp inside: t>=1e-24 <=> norm>=1e-12).
    float inv2[2][4];
#pragma unroll
    for (int i = 0; i < 2; ++i)
#pragma unroll
        for (int r = 0; r < 4; ++r) {
            const int row = i * 16 + quad * 4 + r;
            const float t = red[0][row] + red[1][row] + red[2][row] + red[3][row];
            inv2[i][r] = __builtin_amdgcn_rsqf(fmaxf(t, 1e-24f)) * LOG2E2;
        }

    // v = tanh(t/||t||): vu partials, write v (bf16) into xs (reuse).
    // LAST read of GEMM1's acc -- dead after this loop (enables AGPR reuse).
    float uj[4];
#pragma unroll
    for (int j = 0; j < 4; ++j) uj[j] = u[w * 64 + j * 16 + c];
    float vup[2][4];
#pragma unroll
    for (int i = 0; i < 2; ++i)
#pragma unroll
        for (int r = 0; r < 4; ++r) vup[i][r] = 0.f;
#pragma unroll
    for (int i = 0; i < 2; ++i)
#pragma unroll
        for (int j = 0; j < 4; ++j)
#pragma unroll
            for (int r = 0; r < 4; ++r) {
                const float e2 = __builtin_amdgcn_exp2f(acc[i][j][r] * inv2[i][r]);
                const float v  = (e2 - 1.f) * __builtin_amdgcn_rcpf(e2 + 1.f);
                vup[i][r] += v * uj[j];
                xs[(i * 16 + quad * 4 + r) * XP + (w * 64 + j * 16 + c)] = (__bf16)v;
            }
    // vu partials into red2 BEFORE the barrier (red2 has no prior readers).
    {
        float myv = 0.f;
#pragma unroll
        for (int i = 0; i < 2; ++i)
#pragma unroll
            for (int r = 0; r < 4; ++r) {
                const float p = qred_add(vup[i][r]);
                if (c == i * 4 + r) myv = p;
            }
        if (c < 8) red2[w][(c >> 2) * 16 + quad * 4 + (c & 3)] = myv;
    }
    __syncthreads();                                   // (b): v tile AND vu partials visible

    // early e_out store (ev for epilogue recomputed after (d) from red2, intact)
    if (tid < ROWS) {
        const float vu = red2[0][tid] + red2[1][tid] + red2[2][tid] + red2[3][tid];
        e_out[row0 + tid] = __expf(vu) * mask[row0 + tid];
    }

    // ---- GEMM2: vuo = v @ Uo  (accumulates into the SAME acc array -> AGPR reuse)
#pragma unroll
    for (int i = 0; i < 2; ++i)
#pragma unroll
        for (int j = 0; j < 4; ++j) acc[i][j] = (f32x4){0.f, 0.f, 0.f, 0.f};
#pragma unroll
    for (int kk = 0; kk < 8; ++kk) {
        bf16x8 a[2], b[4];
#pragma unroll
        for (int i = 0; i < 2; ++i)
            a[i] = *(const bf16x8*)(xs + (i * 16 + c) * XP + kk * 32 + quad * 8);
#pragma unroll
        for (int j = 0; j < 4; ++j)
            b[j] = Uf8[(kk * 16 + w * 4 + j) * 64 + lane];
#pragma unroll
        for (int i = 0; i < 2; ++i)
#pragma unroll
            for (int j = 0; j < 4; ++j)
                acc[i][j] = __builtin_amdgcn_mfma_f32_16x16x32_bf16(a[i], b[j], acc[i][j], 0, 0, 0);
    }

    // betas numerator: exp(vuo*m)*m = exp2(vuo*(m*log2e))*m  (no max shift:
    // |vuo| <= ~10, the shift cancels exactly in the ratio)
#pragma unroll
    for (int i = 0; i < 2; ++i)
#pragma unroll
        for (int r = 0; r < 4; ++r) {
            const float m  = mask[row0 + i * 16 + quad * 4 + r];
            const float m2 = m * LOG2E;
#pragma unroll
            for (int j = 0; j < 4; ++j)
                acc[i][j][r] = __builtin_amdgcn_exp2f(acc[i][j][r] * m2) * m;
        }
    // beta row-sum partials into red BEFORE the barrier (red's last reader was
    // inv2, pre-(b): barrier (b) orders -> no WAR hazard). GUARDED store (c<8).
    {
        float myv = 0.f;
#pragma unroll
        for (int i = 0; i < 2; ++i)
#pragma unroll
            for (int r = 0; r < 4; ++r) {
                float s = 0.f;
#pragma unroll
                for (int j = 0; j < 4; ++j) s += acc[i][j][r];
                const float p = qred_add(s);
                if (c == i * 4 + r) myv = p;
            }
        if (c < 8) red[w][(c >> 2) * 16 + quad * 4 + (c & 3)] = myv;
    }
    __syncthreads();                                   // (d): GEMM2 xs reads done (trans WAR)
                                                       //      AND beta sums visible

    // ev + rs in store mapping: row rr = i*16 + hi + p*4
    float ev[2][4], rs[2][4];
#pragma unroll
    for (int i = 0; i < 2; ++i)
#pragma unroll
        for (int p = 0; p < 4; ++p) {
            const int rr = i * 16 + hi + p * 4;
            const float vu = red2[0][rr] + red2[1][rr] + red2[2][rr] + red2[3][rr];
            ev[i][p] = __expf(vu) * mask[row0 + rr];
            const float s = red[0][rr] + red[1][rr] + red[2][rr] + red[3][rr];
            rs[i][p] = __builtin_amdgcn_rcpf((s == 0.f) ? 1.f : s);
        }

    // ---- epilogue: two-pass LDS transpose (16-row wave-private slice) ->
    //      coalesced nontemporal f32x4 stores, fused out-partials with x re-read.
    float* tw = trans + w * (16 * TP);
    f32x4 opart = (f32x4){0.f, 0.f, 0.f, 0.f};
#pragma unroll
    for (int i = 0; i < 2; ++i) {
        asm volatile("s_waitcnt lgkmcnt(0)" ::: "memory");  // WAR: prior trans reads drained
#pragma unroll
        for (int j = 0; j < 4; ++j)
#pragma unroll
            for (int r = 0; r < 4; ++r)
                tw[(quad * 4 + r) * TP + j * 16 + c] = acc[i][j][r];
        asm volatile("s_waitcnt lgkmcnt(0)" ::: "memory");  // RAW: writes visible
#pragma unroll
        for (int p = 0; p < 4; ++p) {
            const int rl = hi + p * 4;                      // local row 0..15
            f32x4 b4 = *(const f32x4*)&tw[rl * TP + c4 * 4];
            const float rsv = rs[i][p];
            b4[0] *= rsv; b4[1] *= rsv; b4[2] *= rsv; b4[3] *= rsv;
            const size_t goff = (size_t)(row0 + i * 16 + rl) * D_ + w * 64 + c4 * 4;
            __builtin_nontemporal_store(b4, (f32x4*)&betas[goff]); // 256 B/16-lane group
            const float evv = ev[i][p];
            if (evv != 0.f) {                               // 16-lane-uniform skip
                const f32x4 x4 = *(const f32x4*)&x[goff];
                opart[0] += evv * b4[0] * x4[0];
                opart[1] += evv * b4[1] * x4[1];
                opart[2] += evv * b4[2] * x4[2];
                opart[3] += evv * b4[3] * x4[3];
            }
        }
    }
    // reduce across the 4 row-groups
#pragma unroll
    for (int k = 0; k < 4; ++k) {
        opart[k] += __shfl_xor(opart[k], 16);
        opart[k] += __shfl_xor(opart[k], 32);
    }
    if (lane < 16) {
        const int col = w * 64 + c4 * 4;
        if (use_part) {
            *(f32x4*)&part[(size_t)blockIdx.x * D_ + col] = opart;
        } else {
            const int b = row0 >> 10;
#pragma unroll
            for (int k = 0; k < 4; ++k) atomicAdd(&outraw[b * D_ + col + k], opart[k]);
        }
    }
}

// ---- final: Z per batch, normalize alphas in place, reduce out partials.
__global__ __launch_bounds__(256) void k_fin(
    const float* __restrict__ part, float* __restrict__ e_alphas,
    float* __restrict__ out, const int use_part)
{
    const int b = blockIdx.x;
    const int tid = threadIdx.x, lane = tid & 63, wid = tid >> 6;
    __shared__ float red[4];
    const int base = b * S_;
    float ev[4];
#pragma unroll
    for (int k = 0; k < 4; ++k) ev[k] = e_alphas[base + tid + 256 * k];
    float s = ev[0] + ev[1] + ev[2] + ev[3];
    s = wred_add(s);
    if (lane == 0) red[wid] = s;
    __syncthreads();
    const float Z = red[0] + red[1] + red[2] + red[3];
    const float Zr = 1.f / ((Z == 0.f) ? 1.f : Z);
#pragma unroll
    for (int k = 0; k < 4; ++k) e_alphas[base + tid + 256 * k] = ev[k] * Zr;

    float acc;
    if (use_part) {
        acc = 0.f;
#pragma unroll
        for (int k = 0; k < 32; ++k) acc += part[(size_t)(b * 32 + k) * D_ + tid];
    } else {
        acc = out[b * D_ + tid];
    }
    out[b * D_ + tid] = acc * Zr;
}

extern "C" void kernel_launch(void* const* d_in, const int* in_sizes, int n_in,
                              void* d_out, int out_size, void* d_ws, size_t ws_size,
                              hipStream_t stream) {
    const float* x    = (const float*)d_in[0];
    const float* mask = (const float*)d_in[1];
    const float* W    = (const float*)d_in[2];
    const float* bo   = (const float*)d_in[3];
    const float* u    = (const float*)d_in[4];
    const float* Uo   = (const float*)d_in[5];

    float* out    = (float*)d_out;             // [B, 256]
    float* alphas = out + B_ * D_;             // [B, S]
    float* betas  = alphas + (size_t)B_ * S_;  // [B, S, 256]

    __bf16* Wf = (__bf16*)d_ws;                // 128 KB
    __bf16* Uf = Wf + 65536;                   // 128 KB
    float* part = (float*)(Uf + 65536);        // 4096*256*4 = 4 MB (if it fits)

    const int nblk = B_ * S_ / ROWS;           // 4096
    const size_t need = 2 * 65536 * sizeof(__bf16) + (size_t)nblk * D_ * sizeof(float);
    const int use_part = (ws_size >= need) ? 1 : 0;

    if (!use_part)
        hipMemsetAsync(out, 0, (size_t)B_ * D_ * sizeof(float), stream);
    k_prep<<<256, 256, 0, stream>>>(W, Uo, Wf, Uf);
    k_rows<<<nblk, 256, 0, stream>>>(x, mask, Wf, bo, u, Uf, alphas, betas, part, out, use_part);
    k_fin <<<B_,   256, 0, stream>>>(part, alphas, out, use_part);
}